// Round 4
// baseline (149.197 us; speedup 1.0000x reference)
//
#include <hip/hip_runtime.h>
#include <math.h>

#define PCEN_EPS 1e-6f

constexpr int Bn = 64, Cn = 80, Tn = 8000;
constexpr int ROWS = Bn * Cn;          // 5120 rows; one block per row
constexpr int WPR  = 4;                // waves per row
constexpr int SEG  = Tn / WPR;         // 2000 elements per wave
constexpr int EPL  = 16;               // elements per lane
constexpr int LCH  = 64 * EPL;         // 1024-element chunk
constexpr int NCH  = 2;                // chunk1 = 976 elems (lanes 0..60)

// pow for strictly-positive base on the HW transcendental pipe
__device__ __forceinline__ float fast_pow_pos(float b, float e) {
#if __has_builtin(__builtin_amdgcn_logf) && __has_builtin(__builtin_amdgcn_exp2f)
    return __builtin_amdgcn_exp2f(e * __builtin_amdgcn_logf(b));
#else
    return __exp2f(e * __log2f(b));
#endif
}

__global__ __launch_bounds__(256, 8)
void pcen_kernel(const float* __restrict__ x,
                 const float* __restrict__ logit_s,
                 const float* __restrict__ alpha,
                 const float* __restrict__ delta,
                 const float* __restrict__ log_r,
                 float* __restrict__ out)
{
    __shared__ float sm[WPR];
    const int lane = threadIdx.x & 63;
    const int wid  = threadIdx.x >> 6;
    const int row  = blockIdx.x;           // one block per (b,c) row
    const int c    = row % Cn;

    // per-channel parameters (broadcast loads)
    const float s  = 1.0f / (1.0f + __expf(-logit_s[c]));
    const float w  = 1.0f - s;
    const float a  = fminf(fmaxf(alpha[c], 0.1f), 1.0f);
    const float dd = fmaxf(delta[c], 0.1f);
    const float rr = fminf(fmaxf(__expf(log_r[c]), 0.05f), 1.5f);
    const float d_r = fast_pow_pos(dd, rr);
    const float na  = -a;

    // w16p[i] = w^(16*2^i), i=0..6, by repeated squaring (no log of ~0)
    float w16p[7];
    {
        const float w2 = w * w, w4 = w2 * w2, w8 = w4 * w4;
        w16p[0] = w8 * w8;
        #pragma unroll
        for (int i = 1; i < 7; ++i) w16p[i] = w16p[i - 1] * w16p[i - 1];
    }
    // per-lane w^(16*lane)
    float w16L = 1.0f;
    #pragma unroll
    for (int b = 0; b < 6; ++b)
        if (lane & (1 << b)) w16L *= w16p[b];
    const float w1024 = w16p[6];
    // w^976 = w^(16*61), 61 = 32+16+8+4+1
    const float w976  = w16p[5] * w16p[4] * w16p[3] * w16p[2] * w16p[0];
    const float w2000 = w1024 * w976;

    const float* __restrict__ xs = x   + (size_t)row * Tn + wid * SEG;
    float* __restrict__ os       = out + (size_t)row * Tn + wid * SEG;

    // ---- all 8 dwordx4 loads issued up-front; relu in place ----
    float xv[NCH][EPL];
    #pragma unroll
    for (int ch = 0; ch < NCH; ++ch) {
        const int base = ch * LCH + lane * EPL;
        if (base + EPL <= SEG) {
            #pragma unroll
            for (int q = 0; q < 4; ++q) {
                const float4 p = *reinterpret_cast<const float4*>(xs + base + 4 * q);
                xv[ch][4 * q + 0] = p.x; xv[ch][4 * q + 1] = p.y;
                xv[ch][4 * q + 2] = p.z; xv[ch][4 * q + 3] = p.w;
            }
        } else {
            #pragma unroll
            for (int j = 0; j < EPL; ++j) xv[ch][j] = 0.0f;
        }
    }
    #pragma unroll
    for (int ch = 0; ch < NCH; ++ch)
        #pragma unroll
        for (int j = 0; j < EPL; ++j) xv[ch][j] = fmaxf(xv[ch][j], 0.0f);

    // wave 0 carry-in: P = relu(x[0]) so m_0 = w*x0 + s*x0 = x0 exactly
    const float p00 = __shfl(xv[0][0], 0, 64);
    float P = (wid == 0) ? p00 : 0.0f;

    // ---- phase A: scan each chunk; keep only per-lane boundary state F ----
    float F0, F1;
    auto scanChunk = [&](const float (&xc)[EPL], float Pprev, float wP,
                         int lastLane, float& Fout) -> float {
        // lane-local Horner end value with carry 0
        float y = s * xc[0];
        #pragma unroll
        for (int j = 1; j < EPL; ++j) y = fmaf(y, w, s * xc[j]);
        // Hillis-Steele inclusive scan across 64 lanes, coefficient w^16
        float Y = y;
        #pragma unroll
        for (int st = 0; st < 6; ++st) {
            const float Yup  = __shfl_up(Y, 1 << st, 64);
            const float cand = fmaf(w16p[st], Yup, Y);
            Y = (lane >= (1 << st)) ? cand : Y;
        }
        const float Yprev = __shfl_up(Y, 1, 64);
        const float excl  = (lane == 0) ? 0.0f : Yprev;
        Fout = fmaf(w16L, Pprev, excl);          // state just before this lane's span
        const float Ylast = __shfl(Y, lastLane, 64);
        return fmaf(wP, Pprev, Ylast);           // chunk carry-out
    };
    P = scanChunk(xv[0], P, w1024, 63, F0);      // chunk 0: 1024 elems
    P = scanChunk(xv[1], P, w976, 60, F1);       // chunk 1: 976 elems (ends lane 60)

    // ---- cross-wave carry combine (exact) ----
    if (lane == 0) sm[wid] = P;
    __syncthreads();
    const float A0 = sm[0];
    const float A1 = fmaf(w2000, A0, sm[1]);
    const float A2 = fmaf(w2000, A1, sm[2]);
    const float Pin = (wid == 1) ? A0 : (wid == 2) ? A1 : (wid == 3) ? A2 : 0.0f;

    // ---- phase B: recompute m from corrected F, pointwise pcen, store ----
    auto emit = [&](const float (&xc)[EPL], float Fc, int base) {
        if (base + EPL <= SEG) {
            float mm = Fc;
            #pragma unroll
            for (int q = 0; q < 4; ++q) {
                float o[4];
                #pragma unroll
                for (int j = 0; j < 4; ++j) {
                    const float xx = xc[4 * q + j];
                    mm = fmaf(w, mm, s * xx);
                    const float t = fast_pow_pos(PCEN_EPS + mm, na);
                    o[j] = fast_pow_pos(fmaf(xx, t, dd), rr) - d_r;
                }
                *reinterpret_cast<float4*>(os + base + 4 * q) =
                    make_float4(o[0], o[1], o[2], o[3]);
            }
        }
    };
    emit(xv[0], fmaf(w16L, Pin, F0), lane * EPL);
    emit(xv[1], fmaf(w1024 * w16L, Pin, F1), LCH + lane * EPL);
}

extern "C" void kernel_launch(void* const* d_in, const int* in_sizes, int n_in,
                              void* d_out, int out_size, void* d_ws, size_t ws_size,
                              hipStream_t stream) {
    const float* features = (const float*)d_in[0];
    const float* logit_s  = (const float*)d_in[1];
    const float* alpha    = (const float*)d_in[2];
    const float* delta    = (const float*)d_in[3];
    const float* log_r    = (const float*)d_in[4];
    float* out = (float*)d_out;

    // one block per row: 5120 blocks x 256 threads = 20480 waves
    pcen_kernel<<<ROWS, WPR * 64, 0, stream>>>(features, logit_s, alpha, delta, log_r, out);
}

// Round 5
// 80.414 us; speedup vs baseline: 1.8554x; 1.8554x over previous
//
#include <hip/hip_runtime.h>
#include <math.h>

#define PCEN_EPS 1e-6f

constexpr int Bn = 64, Cn = 80, Tn = 8000;
constexpr int ROWS = Bn * Cn;          // 5120 rows; one block per row
constexpr int WPR  = 4;                // waves per row
constexpr int SEG  = Tn / WPR;         // 2000 elements per wave
constexpr int EPL  = 16;               // elements per lane
constexpr int LCH  = 64 * EPL;         // 1024-element chunk
constexpr int NCH  = 2;                // chunk1 = 976 elems (lanes 0..60)

// pow for strictly-positive base on the HW transcendental pipe
__device__ __forceinline__ float fast_pow_pos(float b, float e) {
#if __has_builtin(__builtin_amdgcn_logf) && __has_builtin(__builtin_amdgcn_exp2f)
    return __builtin_amdgcn_exp2f(e * __builtin_amdgcn_logf(b));
#else
    return __exp2f(e * __log2f(b));
#endif
}

// NOTE R4 lesson: __launch_bounds__(256,8) forced a 32-VGPR budget -> the
// xv[2][16] live set spilled to scratch (WRITE_SIZE 478MB vs 160MB real).
// (256,4) = 128-VGPR cap: no spills; occupancy comes from actual alloc.
__global__ __launch_bounds__(256, 4)
void pcen_kernel(const float* __restrict__ x,
                 const float* __restrict__ logit_s,
                 const float* __restrict__ alpha,
                 const float* __restrict__ delta,
                 const float* __restrict__ log_r,
                 float* __restrict__ out)
{
    __shared__ float sm[WPR];
    const int lane = threadIdx.x & 63;
    const int wid  = threadIdx.x >> 6;
    const int row  = blockIdx.x;           // one block per (b,c) row
    const int c    = row % Cn;

    // per-channel parameters (broadcast loads)
    const float s  = 1.0f / (1.0f + __expf(-logit_s[c]));
    const float w  = 1.0f - s;
    const float a  = fminf(fmaxf(alpha[c], 0.1f), 1.0f);
    const float dd = fmaxf(delta[c], 0.1f);
    const float rr = fminf(fmaxf(__expf(log_r[c]), 0.05f), 1.5f);
    const float d_r = fast_pow_pos(dd, rr);
    const float na  = -a;

    // w16p[i] = w^(16*2^i), i=0..6, by repeated squaring (no log of ~0)
    float w16p[7];
    {
        const float w2 = w * w, w4 = w2 * w2, w8 = w4 * w4;
        w16p[0] = w8 * w8;
        #pragma unroll
        for (int i = 1; i < 7; ++i) w16p[i] = w16p[i - 1] * w16p[i - 1];
    }
    // per-lane w^(16*lane)
    float w16L = 1.0f;
    #pragma unroll
    for (int b = 0; b < 6; ++b)
        if (lane & (1 << b)) w16L *= w16p[b];
    const float w1024 = w16p[6];
    // w^976 = w^(16*61), 61 = 32+16+8+4+1
    const float w976  = w16p[5] * w16p[4] * w16p[3] * w16p[2] * w16p[0];
    const float w2000 = w1024 * w976;

    const float* __restrict__ xs = x   + (size_t)row * Tn + wid * SEG;
    float* __restrict__ os       = out + (size_t)row * Tn + wid * SEG;

    // ---- all 8 dwordx4 loads issued up-front; relu in place ----
    float xv[NCH][EPL];
    #pragma unroll
    for (int ch = 0; ch < NCH; ++ch) {
        const int base = ch * LCH + lane * EPL;
        if (base + EPL <= SEG) {
            #pragma unroll
            for (int q = 0; q < 4; ++q) {
                const float4 p = *reinterpret_cast<const float4*>(xs + base + 4 * q);
                xv[ch][4 * q + 0] = p.x; xv[ch][4 * q + 1] = p.y;
                xv[ch][4 * q + 2] = p.z; xv[ch][4 * q + 3] = p.w;
            }
        } else {
            #pragma unroll
            for (int j = 0; j < EPL; ++j) xv[ch][j] = 0.0f;
        }
    }
    #pragma unroll
    for (int ch = 0; ch < NCH; ++ch)
        #pragma unroll
        for (int j = 0; j < EPL; ++j) xv[ch][j] = fmaxf(xv[ch][j], 0.0f);

    // wave 0 carry-in: P = relu(x[0]) so m_0 = w*x0 + s*x0 = x0 exactly
    const float p00 = __shfl(xv[0][0], 0, 64);
    float P = (wid == 0) ? p00 : 0.0f;

    // ---- phase A: scan each chunk; keep only per-lane boundary state F ----
    float F0, F1;
    auto scanChunk = [&](const float (&xc)[EPL], float Pprev, float wP,
                         int lastLane, float& Fout) -> float {
        // lane-local Horner end value with carry 0
        float y = s * xc[0];
        #pragma unroll
        for (int j = 1; j < EPL; ++j) y = fmaf(y, w, s * xc[j]);
        // Hillis-Steele inclusive scan across 64 lanes, coefficient w^16
        float Y = y;
        #pragma unroll
        for (int st = 0; st < 6; ++st) {
            const float Yup  = __shfl_up(Y, 1 << st, 64);
            const float cand = fmaf(w16p[st], Yup, Y);
            Y = (lane >= (1 << st)) ? cand : Y;
        }
        const float Yprev = __shfl_up(Y, 1, 64);
        const float excl  = (lane == 0) ? 0.0f : Yprev;
        Fout = fmaf(w16L, Pprev, excl);          // state just before this lane's span
        const float Ylast = __shfl(Y, lastLane, 64);
        return fmaf(wP, Pprev, Ylast);           // chunk carry-out
    };
    P = scanChunk(xv[0], P, w1024, 63, F0);      // chunk 0: 1024 elems
    P = scanChunk(xv[1], P, w976, 60, F1);       // chunk 1: 976 elems (ends lane 60)

    // ---- cross-wave carry combine (exact) ----
    if (lane == 0) sm[wid] = P;
    __syncthreads();
    const float A0 = sm[0];
    const float A1 = fmaf(w2000, A0, sm[1]);
    const float A2 = fmaf(w2000, A1, sm[2]);
    const float Pin = (wid == 1) ? A0 : (wid == 2) ? A1 : (wid == 3) ? A2 : 0.0f;

    // ---- phase B: recompute m from corrected F, pointwise pcen, store ----
    auto emit = [&](const float (&xc)[EPL], float Fc, int base) {
        if (base + EPL <= SEG) {
            float mm = Fc;
            #pragma unroll
            for (int q = 0; q < 4; ++q) {
                float o[4];
                #pragma unroll
                for (int j = 0; j < 4; ++j) {
                    const float xx = xc[4 * q + j];
                    mm = fmaf(w, mm, s * xx);
                    const float t = fast_pow_pos(PCEN_EPS + mm, na);
                    o[j] = fast_pow_pos(fmaf(xx, t, dd), rr) - d_r;
                }
                *reinterpret_cast<float4*>(os + base + 4 * q) =
                    make_float4(o[0], o[1], o[2], o[3]);
            }
        }
    };
    emit(xv[0], fmaf(w16L, Pin, F0), lane * EPL);
    emit(xv[1], fmaf(w1024 * w16L, Pin, F1), LCH + lane * EPL);
}

extern "C" void kernel_launch(void* const* d_in, const int* in_sizes, int n_in,
                              void* d_out, int out_size, void* d_ws, size_t ws_size,
                              hipStream_t stream) {
    const float* features = (const float*)d_in[0];
    const float* logit_s  = (const float*)d_in[1];
    const float* alpha    = (const float*)d_in[2];
    const float* delta    = (const float*)d_in[3];
    const float* log_r    = (const float*)d_in[4];
    float* out = (float*)d_out;

    // one block per row: 5120 blocks x 256 threads = 20480 waves
    pcen_kernel<<<ROWS, WPR * 64, 0, stream>>>(features, logit_s, alpha, delta, log_r, out);
}